// Round 1
// baseline (585.040 us; speedup 1.0000x reference)
//
#include <hip/hip_runtime.h>
#include <hip/hip_cooperative_groups.h>
#include <math.h>

#define E 1280
#define NHEAD 20
#define HD 64
#define NBLK 7
#define NBATCH 64
#define GRID 512
#define NTILE_QKV (3 * E / 16)   // 240
#define NTILE_O   (E / 16)       // 80

namespace cg = cooperative_groups;

typedef __bf16 bf16x8 __attribute__((ext_vector_type(8)));
typedef __bf16 bf16x4 __attribute__((ext_vector_type(4)));
typedef float floatx4 __attribute__((ext_vector_type(4)));

__device__ __forceinline__ float wave_max64(float v) {
#pragma unroll
    for (int o = 32; o > 0; o >>= 1) v = fmaxf(v, __shfl_xor(v, o, 64));
    return v;
}
__device__ __forceinline__ float wave_sum64(float v) {
#pragma unroll
    for (int o = 32; o > 0; o >>= 1) v += __shfl_xor(v, o, 64);
    return v;
}
__device__ __forceinline__ bf16x4 cvt4(float4 v) {
    bf16x4 p;
    p[0] = (__bf16)v.x; p[1] = (__bf16)v.y; p[2] = (__bf16)v.z; p[3] = (__bf16)v.w;
    return p;
}

// ---- 64x16 GEMM tile: C[row][jg0+j] = (sum_k A[row][k]*Wp[j0+j][k] + bp[j0+j])*scl
// 4 waves, wave-split-K (320 each), wave-private LDS (no barriers in K-loop),
// register double-buffer prefetch: chunk c+1's global loads in flight while
// chunk c is converted/written/MFMA'd (counted vmcnt overlap).
__device__ __forceinline__ void gemm_tile(
    const float* __restrict__ A, const float* __restrict__ Wp,
    const float* __restrict__ bp, const float scl,
    const int j0, const int jg0, const int ldC, float* __restrict__ C)
{
    __shared__ __align__(16) __bf16 Asl[4][64][72];   // 36 KB, [wv]-private
    __shared__ __align__(16) __bf16 Wsl[4][16][72];   // 9 KB,  [wv]-private

    const int t = threadIdx.x;
    const int lane = t & 63;
    const int wv = t >> 6;
    const int quad = lane >> 4;
    const int l16 = lane & 15;
    const int sr = lane >> 2;     // staging row 0..15
    const int sc = lane & 3;      // float4 index within 16-float run

    floatx4 acc[4] = {};
    const int kbeg = wv * (E / 4);           // 320 per wave

    // preload chunk 0 into registers
    float4 Ab[16], Wb[4];
#pragma unroll
    for (int rg = 0; rg < 4; ++rg)
#pragma unroll
        for (int cg = 0; cg < 4; ++cg)
            Ab[rg * 4 + cg] = *(const float4*)&A[(size_t)(rg * 16 + sr) * E + kbeg + cg * 16 + sc * 4];
#pragma unroll
    for (int cg = 0; cg < 4; ++cg)
        Wb[cg] = *(const float4*)&Wp[(size_t)(j0 + sr) * E + kbeg + cg * 16 + sc * 4];

#pragma unroll
    for (int c = 0; c < 5; ++c) {
        float4 An[16], Wn[4];
        if (c < 4) {   // issue next chunk's loads before touching current chunk
            const int k1 = kbeg + (c + 1) * 64;
#pragma unroll
            for (int rg = 0; rg < 4; ++rg)
#pragma unroll
                for (int cg = 0; cg < 4; ++cg)
                    An[rg * 4 + cg] = *(const float4*)&A[(size_t)(rg * 16 + sr) * E + k1 + cg * 16 + sc * 4];
#pragma unroll
            for (int cg = 0; cg < 4; ++cg)
                Wn[cg] = *(const float4*)&Wp[(size_t)(j0 + sr) * E + k1 + cg * 16 + sc * 4];
        }
        // cvt + wave-private LDS write; in-wave ds ordering via lgkmcnt only
#pragma unroll
        for (int rg = 0; rg < 4; ++rg)
#pragma unroll
            for (int cg = 0; cg < 4; ++cg)
                *(bf16x4*)&Asl[wv][rg * 16 + sr][cg * 16 + sc * 4] = cvt4(Ab[rg * 4 + cg]);
#pragma unroll
        for (int cg = 0; cg < 4; ++cg)
            *(bf16x4*)&Wsl[wv][sr][cg * 16 + sc * 4] = cvt4(Wb[cg]);

        bf16x8 bfr0 = *(const bf16x8*)&Wsl[wv][l16][quad * 8];
        bf16x8 bfr1 = *(const bf16x8*)&Wsl[wv][l16][32 + quad * 8];
#pragma unroll
        for (int rg = 0; rg < 4; ++rg) {
            bf16x8 af0 = *(const bf16x8*)&Asl[wv][rg * 16 + l16][quad * 8];
            acc[rg] = __builtin_amdgcn_mfma_f32_16x16x32_bf16(af0, bfr0, acc[rg], 0, 0, 0);
            bf16x8 af1 = *(const bf16x8*)&Asl[wv][rg * 16 + l16][32 + quad * 8];
            acc[rg] = __builtin_amdgcn_mfma_f32_16x16x32_bf16(af1, bfr1, acc[rg], 0, 0, 0);
        }
        if (c < 4) {
#pragma unroll
            for (int i = 0; i < 16; ++i) Ab[i] = An[i];
#pragma unroll
            for (int i = 0; i < 4; ++i) Wb[i] = Wn[i];
        }
    }

    // cross-wave reduction through LDS (alias first 16 KB of Asl)
    __syncthreads();
    float (*Cred)[64][16] = (float (*)[64][16])&Asl[0][0][0];
    // C/D layout: col = lane&15, row = quad*4 + reg (m89-verified)
#pragma unroll
    for (int rg = 0; rg < 4; ++rg)
#pragma unroll
        for (int r = 0; r < 4; ++r)
            Cred[wv][rg * 16 + quad * 4 + r][l16] = acc[rg][r];
    __syncthreads();
#pragma unroll
    for (int i = 0; i < 4; ++i) {
        const int e = t + i * 256;
        const int row = e >> 4, col = e & 15;
        float s = Cred[0][row][col] + Cred[1][row][col]
                + Cred[2][row][col] + Cred[3][row][col];
        C[(size_t)row * ldC + jg0 + col] = (s + bp[j0 + col]) * scl;
    }
    __syncthreads();
}

__device__ __forceinline__ void qkv_tile(
    const int tile, const float* __restrict__ hidden,
    const float* __restrict__ wq, const float* __restrict__ bq,
    const float* __restrict__ wk, const float* __restrict__ bk,
    const float* __restrict__ wv_, const float* __restrict__ bv,
    float* __restrict__ qkv)
{
    const int jg0 = tile * 16;
    const int msel = jg0 / E;
    const int j0 = jg0 - msel * E;
    const float* Wp = (msel == 0) ? wq : ((msel == 1) ? wk : wv_);
    const float* bp = (msel == 0) ? bq : ((msel == 1) ? bk : bv);
    const float scl = (msel == 0) ? 0.125f : 1.0f;
    gemm_tile(hidden, Wp, bp, scl, j0, jg0, 3 * E, qkv);
}

// ---- flash attention for one (b,h); 4 waves, 1 KV block per wave per iter ----
__device__ __forceinline__ void attn_unit(
    const int bh, const float* __restrict__ qkv,
    const float* __restrict__ kcache, const float* __restrict__ vcache,
    const int* __restrict__ cache_position, const int* __restrict__ block_tables,
    float* __restrict__ obuf)
{
    __shared__ __align__(16) float q_lds[64];
    __shared__ __align__(16) float o_lds[4][64];
    __shared__ float ml_lds[4][2];

    const int b = bh / NHEAD;
    const int h = bh - b * NHEAD;
    const int lane = threadIdx.x & 63;
    const int wv = threadIdx.x >> 6;
    const int d4 = lane & 15;
    const int sg = lane >> 4;

    const int pos = cache_position[b];
    const int last = pos - 1;
    const int col = h * HD + lane;

    const float qd  = qkv[(size_t)b * (3 * E) + col];
    const float knd = qkv[(size_t)b * (3 * E) + E + col];
    const float vnd = qkv[(size_t)b * (3 * E) + 2 * E + col];
    if (wv == 0) q_lds[lane] = qd;
    __syncthreads();

    float m = -INFINITY, lsum = 0.0f;
    float4 vacc = make_float4(0.f, 0.f, 0.f, 0.f);

    for (int nb = wv; nb * 64 <= last; nb += 4) {
        const int phys = block_tables[b * NBLK + nb];
        const size_t boff = ((size_t)((b * NHEAD + h) * NBLK + phys)) << 12; // *64*64
        const float* __restrict__ Kb = kcache + boff;
        const float* __restrict__ Vb = vcache + boff;

        float sc = 0.0f;
        const float4* Krow = (const float4*)(Kb + lane * HD);
#pragma unroll
        for (int dd = 0; dd < 16; ++dd) {
            float4 k4 = Krow[dd];
            float4 q4 = ((const float4*)q_lds)[dd];
            sc = fmaf(k4.x, q4.x, sc);
            sc = fmaf(k4.y, q4.y, sc);
            sc = fmaf(k4.z, q4.z, sc);
            sc = fmaf(k4.w, q4.w, sc);
        }
        const int l = nb * 64 + lane;
        if (l > last) sc = -INFINITY;

        const float bm = wave_max64(sc);
        const float mnew = fmaxf(m, bm);
        const float alpha = __expf(m - mnew);
        const float p = __expf(sc - mnew);
        lsum = lsum * alpha + wave_sum64(p);
        vacc.x *= alpha; vacc.y *= alpha; vacc.z *= alpha; vacc.w *= alpha;

#pragma unroll
        for (int j = 0; j < 16; ++j) {
            const int s = sg + 4 * j;
            const float ps = __shfl(p, s, 64);
            float4 v4 = *(const float4*)&Vb[s * HD + d4 * 4];
            vacc.x = fmaf(ps, v4.x, vacc.x);
            vacc.y = fmaf(ps, v4.y, vacc.y);
            vacc.z = fmaf(ps, v4.z, vacc.z);
            vacc.w = fmaf(ps, v4.w, vacc.w);
        }
        m = mnew;
    }

#pragma unroll
    for (int o = 16; o <= 32; o <<= 1) {
        vacc.x += __shfl_xor(vacc.x, o, 64);
        vacc.y += __shfl_xor(vacc.y, o, 64);
        vacc.z += __shfl_xor(vacc.z, o, 64);
        vacc.w += __shfl_xor(vacc.w, o, 64);
    }
    if (sg == 0) *(float4*)&o_lds[wv][d4 * 4] = vacc;
    if (lane == 0) { ml_lds[wv][0] = m; ml_lds[wv][1] = lsum; }
    __syncthreads();

    if (wv == 0) {
        const float qk = wave_sum64(qd * knd);   // new-token score (finite)
        float Mf = qk;
#pragma unroll
        for (int w = 0; w < 4; ++w) Mf = fmaxf(Mf, ml_lds[w][0]);
        float osum = 0.0f, Ls = 0.0f;
#pragma unroll
        for (int w = 0; w < 4; ++w) {
            const float f = __expf(ml_lds[w][0] - Mf);   // 0 for empty waves
            osum = fmaf(o_lds[w][lane], f, osum);
            Ls   = fmaf(ml_lds[w][1], f, Ls);
        }
        const float pn = __expf(qk - Mf);
        osum = fmaf(pn, vnd, osum);
        Ls += pn;
        obuf[(size_t)b * E + h * HD + lane] = osum / Ls;
    }
    __syncthreads();   // protect LDS reuse by the next unit
}

// ---- fused cooperative kernel: QKV -> grid.sync -> attn -> grid.sync -> O-proj
__global__ __launch_bounds__(256, 2) void fused_kernel(
    const float* __restrict__ hidden,
    const float* __restrict__ kcache, const float* __restrict__ vcache,
    const float* __restrict__ wq, const float* __restrict__ bq,
    const float* __restrict__ wk, const float* __restrict__ bk,
    const float* __restrict__ wv_, const float* __restrict__ bv,
    const float* __restrict__ wo, const float* __restrict__ bo,
    const int* __restrict__ cpos, const int* __restrict__ btab,
    float* __restrict__ out, float* __restrict__ qkv, float* __restrict__ ob)
{
    const int bb = blockIdx.x;
    cg::grid_group grid = cg::this_grid();

    // Phase A: QKV projection (240 tiles; 272 blocks idle through this short phase)
    if (bb < NTILE_QKV)
        qkv_tile(bb, hidden, wq, bq, wk, bk, wv_, bv, qkv);

    __threadfence();   // device-scope release for cross-XCD readers
    grid.sync();

    // Phase B: attention, 1280 (b,h) units over 512 blocks (2-3 each)
    for (int u = bb; u < NBATCH * NHEAD; u += GRID)
        attn_unit(u, qkv, kcache, vcache, cpos, btab, ob);

    __threadfence();
    grid.sync();

    // Phase C: output projection (80 tiles), bias fused, direct to d_out
    if (bb < NTILE_O)
        gemm_tile(ob, wo, bo, 1.0f, bb * 16, bb * 16, E, out);
}

// ---- fallback path (identical math, 3 dispatches) in case cooperative
// launch is rejected by the runtime/capture ----
__global__ __launch_bounds__(256) void qkv_kernel_sep(
    const float* __restrict__ hidden,
    const float* __restrict__ wq, const float* __restrict__ bq,
    const float* __restrict__ wk, const float* __restrict__ bk,
    const float* __restrict__ wv_, const float* __restrict__ bv,
    float* __restrict__ qkv)
{
    qkv_tile(blockIdx.x, hidden, wq, bq, wk, bk, wv_, bv, qkv);
}
__global__ __launch_bounds__(256) void attn_kernel_sep(
    const float* __restrict__ qkv,
    const float* __restrict__ kcache, const float* __restrict__ vcache,
    const int* __restrict__ cpos, const int* __restrict__ btab,
    float* __restrict__ ob)
{
    attn_unit(blockIdx.x, qkv, kcache, vcache, cpos, btab, ob);
}
__global__ __launch_bounds__(256) void oproj_kernel_sep(
    const float* __restrict__ ob,
    const float* __restrict__ wo, const float* __restrict__ bo,
    float* __restrict__ out)
{
    gemm_tile(ob, wo, bo, 1.0f, blockIdx.x * 16, blockIdx.x * 16, E, out);
}

extern "C" void kernel_launch(void* const* d_in, const int* in_sizes, int n_in,
                              void* d_out, int out_size, void* d_ws, size_t ws_size,
                              hipStream_t stream) {
    const float* hidden = (const float*)d_in[0];
    const float* kcache = (const float*)d_in[1];
    const float* vcache = (const float*)d_in[2];
    const float* wq = (const float*)d_in[3];
    const float* bq = (const float*)d_in[4];
    const float* wk = (const float*)d_in[5];
    const float* bk = (const float*)d_in[6];
    const float* wvp = (const float*)d_in[7];
    const float* bv = (const float*)d_in[8];
    const float* wo = (const float*)d_in[9];
    const float* bo = (const float*)d_in[10];
    const int* cpos = (const int*)d_in[11];
    const int* btab = (const int*)d_in[12];
    float* out = (float*)d_out;

    // ws footprint: 64*3840 + 64*1280 floats = 1.31 MB (unchanged, proven safe)
    float* ws = (float*)d_ws;
    float* qkv = ws;                  // 64 x 3840 (q|k|v, bias+scale applied)
    float* ob  = ws + 64 * 3 * E;     // 64 x 1280

    void* args[16] = {
        (void*)&hidden, (void*)&kcache, (void*)&vcache,
        (void*)&wq, (void*)&bq, (void*)&wk, (void*)&bk,
        (void*)&wvp, (void*)&bv, (void*)&wo, (void*)&bo,
        (void*)&cpos, (void*)&btab, (void*)&out, (void*)&qkv, (void*)&ob
    };
    hipError_t err = hipLaunchCooperativeKernel(
        (const void*)fused_kernel, dim3(GRID), dim3(256), args, 0, stream);
    if (err != hipSuccess) {
        (void)hipGetLastError();   // clear sticky error; use proven 3-kernel path
        qkv_kernel_sep<<<NTILE_QKV, 256, 0, stream>>>(hidden, wq, bq, wk, bk, wvp, bv, qkv);
        attn_kernel_sep<<<NBATCH * NHEAD, 256, 0, stream>>>(qkv, kcache, vcache, cpos, btab, ob);
        oproj_kernel_sep<<<NTILE_O, 256, 0, stream>>>(ob, wo, bo, out);
    }
}

// Round 2
// 326.287 us; speedup vs baseline: 1.7930x; 1.7930x over previous
//
#include <hip/hip_runtime.h>
#include <math.h>

#define E 1280
#define NHEAD 20
#define HD 64
#define NBLK 7
#define NBATCH 64

typedef __bf16 bf16x8 __attribute__((ext_vector_type(8)));
typedef float floatx4 __attribute__((ext_vector_type(4)));

__device__ __forceinline__ float wave_max64(float v) {
#pragma unroll
    for (int o = 32; o > 0; o >>= 1) v = fmaxf(v, __shfl_xor(v, o, 64));
    return v;
}
__device__ __forceinline__ float wave_sum64(float v) {
#pragma unroll
    for (int o = 32; o > 0; o >>= 1) v += __shfl_xor(v, o, 64);
    return v;
}
__device__ __forceinline__ bf16x8 cvt8(float4 lo, float4 hi) {
    bf16x8 r;
    r[0] = (__bf16)lo.x; r[1] = (__bf16)lo.y; r[2] = (__bf16)lo.z; r[3] = (__bf16)lo.w;
    r[4] = (__bf16)hi.x; r[5] = (__bf16)hi.y; r[6] = (__bf16)hi.z; r[7] = (__bf16)hi.w;
    return r;
}

// C[row][jg0+j] = (sum_k A[row][k]*Wp[j0+j][k] + bp[j0+j]) * scl
// 64x16 tile / block, 4 waves, wave-split-K (320 each).
// NO LDS in the K-loop: MFMA fragments are contiguous 32B runs in global
// (row=l16, k=quad*8..+7) -> direct float4x2 loads + in-register bf16 cvt.
// Register double-buffer: chunk c+1's 20 float4 loads issued before chunk c's
// cvt+MFMA (counted vmcnt overlap). LDS only for the final cross-wave reduce.
template<int NTOT, bool QKV>
__global__ __launch_bounds__(256) void mfma_gemm(
    const float* __restrict__ A,
    const float* __restrict__ W0, const float* __restrict__ W1,
    const float* __restrict__ W2,
    const float* __restrict__ b0, const float* __restrict__ b1,
    const float* __restrict__ b2,
    float* __restrict__ C)
{
    __shared__ __align__(16) float Cred[4][64][16];   // 16 KB

    const int t = threadIdx.x;
    const int lane = t & 63;
    const int wv = t >> 6;
    const int quad = lane >> 4;
    const int l16 = lane & 15;
    const int jg0 = blockIdx.x * 16;

    int j0; const float* Wp; const float* bp; float scl;
    if (QKV) {
        const int msel = jg0 / E;
        j0 = jg0 - msel * E;
        Wp = (msel == 0) ? W0 : ((msel == 1) ? W1 : W2);
        bp = (msel == 0) ? b0 : ((msel == 1) ? b1 : b2);
        scl = (msel == 0) ? 0.125f : 1.0f;
    } else { j0 = jg0; Wp = W0; bp = b0; scl = 1.0f; }

    const int kbeg = wv * (E / 4);    // 320 per wave
    const int ko = quad * 8;          // fragment k-offset within 64-chunk

    const float* __restrict__ wrow = Wp + (size_t)(j0 + l16) * E;
    const float* __restrict__ arow = A + (size_t)l16 * E;

    floatx4 acc[4] = {};
    float4 Ac[16], Wc[4];

    // chunk 0 preload
    {
        const int k0 = kbeg;
#pragma unroll
        for (int rg = 0; rg < 4; ++rg) {
            const float* ar = arow + (size_t)rg * 16 * E + k0 + ko;
            Ac[rg * 4 + 0] = *(const float4*)(ar);
            Ac[rg * 4 + 1] = *(const float4*)(ar + 4);
            Ac[rg * 4 + 2] = *(const float4*)(ar + 32);
            Ac[rg * 4 + 3] = *(const float4*)(ar + 36);
        }
        const float* wr = wrow + k0 + ko;
        Wc[0] = *(const float4*)(wr);
        Wc[1] = *(const float4*)(wr + 4);
        Wc[2] = *(const float4*)(wr + 32);
        Wc[3] = *(const float4*)(wr + 36);
    }

#pragma unroll
    for (int c = 0; c < 5; ++c) {
        float4 An[16], Wn[4];
        if (c < 4) {   // issue next chunk's loads before touching current
            const int k1 = kbeg + (c + 1) * 64;
#pragma unroll
            for (int rg = 0; rg < 4; ++rg) {
                const float* ar = arow + (size_t)rg * 16 * E + k1 + ko;
                An[rg * 4 + 0] = *(const float4*)(ar);
                An[rg * 4 + 1] = *(const float4*)(ar + 4);
                An[rg * 4 + 2] = *(const float4*)(ar + 32);
                An[rg * 4 + 3] = *(const float4*)(ar + 36);
            }
            const float* wr = wrow + k1 + ko;
            Wn[0] = *(const float4*)(wr);
            Wn[1] = *(const float4*)(wr + 4);
            Wn[2] = *(const float4*)(wr + 32);
            Wn[3] = *(const float4*)(wr + 36);
        }
        const bf16x8 bf0 = cvt8(Wc[0], Wc[1]);
        const bf16x8 bf1 = cvt8(Wc[2], Wc[3]);
#pragma unroll
        for (int rg = 0; rg < 4; ++rg) {
            acc[rg] = __builtin_amdgcn_mfma_f32_16x16x32_bf16(
                cvt8(Ac[rg * 4 + 0], Ac[rg * 4 + 1]), bf0, acc[rg], 0, 0, 0);
            acc[rg] = __builtin_amdgcn_mfma_f32_16x16x32_bf16(
                cvt8(Ac[rg * 4 + 2], Ac[rg * 4 + 3]), bf1, acc[rg], 0, 0, 0);
        }
        if (c < 4) {
#pragma unroll
            for (int i = 0; i < 16; ++i) Ac[i] = An[i];
#pragma unroll
            for (int i = 0; i < 4; ++i) Wc[i] = Wn[i];
        }
    }

    // cross-wave K-reduction through LDS.
    // C/D layout: col = lane&15, row = quad*4 + reg (m89-verified)
#pragma unroll
    for (int rg = 0; rg < 4; ++rg)
#pragma unroll
        for (int r = 0; r < 4; ++r)
            Cred[wv][rg * 16 + quad * 4 + r][l16] = acc[rg][r];
    __syncthreads();
#pragma unroll
    for (int i = 0; i < 4; ++i) {
        const int e = t + i * 256;
        const int row = e >> 4, col = e & 15;
        float s = Cred[0][row][col] + Cred[1][row][col]
                + Cred[2][row][col] + Cred[3][row][col];
        C[(size_t)row * NTOT + jg0 + col] = (s + bp[j0 + col]) * scl;
    }
}

// One block per (b,h), 4 waves. Wave wv owns KV blocks {wv, wv+4} (max logical
// block index is 6, so <=2 per wave). Both blocks are merged into ONE
// single-pass softmax: sc0,sc1 -> one max-reduce -> one sum-reduce -> PV.
// No online rescale (single pass per wave); cross-wave combine via LDS m/l.
__global__ __launch_bounds__(256) void attn_kernel(
    const float* __restrict__ qkv,
    const float* __restrict__ kcache, const float* __restrict__ vcache,
    const int* __restrict__ cache_position, const int* __restrict__ block_tables,
    float* __restrict__ obuf)
{
    const int bh = blockIdx.x;
    const int b = bh / NHEAD;
    const int h = bh - b * NHEAD;
    const int lane = threadIdx.x & 63;
    const int wv = threadIdx.x >> 6;
    const int d4 = lane & 15;        // float4 group in d
    const int sg = lane >> 4;        // slot subgroup

    __shared__ __align__(16) float q_lds[64];
    __shared__ __align__(16) float o_lds[4][64];
    __shared__ float ml_lds[4][2];

    const int pos = cache_position[b];
    const int last = pos - 1;
    const int col = h * HD + lane;

    const float qd  = qkv[(size_t)b * (3 * E) + col];
    const float knd = qkv[(size_t)b * (3 * E) + E + col];
    const float vnd = qkv[(size_t)b * (3 * E) + 2 * E + col];
    if (wv == 0) q_lds[lane] = qd;
    __syncthreads();

    float m = -INFINITY, lsum = 0.0f;
    float4 vacc = make_float4(0.f, 0.f, 0.f, 0.f);

    const int nb0 = wv;
    const int nb1 = wv + 4;
    const bool hasb0 = (nb0 * 64 <= last);
    const bool hasb1 = (nb1 * 64 <= last);    // nb1<=7; guarded -> never OOB

    if (hasb0) {
        const size_t bhoff = (size_t)(b * NHEAD + h) * NBLK;
        const int phys0 = block_tables[b * NBLK + nb0];
        const float* __restrict__ Kb0 = kcache + ((bhoff + phys0) << 12);
        const float* __restrict__ Vb0 = vcache + ((bhoff + phys0) << 12);
        const float* __restrict__ Kb1 = Kb0;
        const float* __restrict__ Vb1 = Vb0;
        if (hasb1) {
            const int phys1 = block_tables[b * NBLK + nb1];
            Kb1 = kcache + ((bhoff + phys1) << 12);
            Vb1 = vcache + ((bhoff + phys1) << 12);
        }

        // scores: lane = slot within block
        float sc0 = 0.0f, sc1 = -INFINITY;
        {
            const float4* Krow = (const float4*)(Kb0 + lane * HD);
#pragma unroll
            for (int dd = 0; dd < 16; ++dd) {
                float4 k4 = Krow[dd];
                float4 q4 = ((const float4*)q_lds)[dd];
                sc0 = fmaf(k4.x, q4.x, sc0);
                sc0 = fmaf(k4.y, q4.y, sc0);
                sc0 = fmaf(k4.z, q4.z, sc0);
                sc0 = fmaf(k4.w, q4.w, sc0);
            }
            if (nb0 * 64 + lane > last) sc0 = -INFINITY;
        }
        if (hasb1) {
            float s1 = 0.0f;
            const float4* Krow = (const float4*)(Kb1 + lane * HD);
#pragma unroll
            for (int dd = 0; dd < 16; ++dd) {
                float4 k4 = Krow[dd];
                float4 q4 = ((const float4*)q_lds)[dd];
                s1 = fmaf(k4.x, q4.x, s1);
                s1 = fmaf(k4.y, q4.y, s1);
                s1 = fmaf(k4.z, q4.z, s1);
                s1 = fmaf(k4.w, q4.w, s1);
            }
            sc1 = (nb1 * 64 + lane > last) ? -INFINITY : s1;
        }

        // prefetch V0 into registers; loads overlap the shuffle reductions
        float4 v0r[16];
#pragma unroll
        for (int j = 0; j < 16; ++j)
            v0r[j] = *(const float4*)&Vb0[(sg + 4 * j) * HD + d4 * 4];

        // single-pass softmax over both blocks (m_ finite: slot nb0*64 valid)
        const float m_ = wave_max64(fmaxf(sc0, sc1));
        const float p0 = __expf(sc0 - m_);   // 0 for masked lanes
        const float p1 = __expf(sc1 - m_);   // 0 if masked / no block1
        lsum = wave_sum64(p0 + p1);
        m = m_;

#pragma unroll
        for (int j = 0; j < 16; ++j) {
            const float ps = __shfl(p0, sg + 4 * j, 64);
            vacc.x = fmaf(ps, v0r[j].x, vacc.x);
            vacc.y = fmaf(ps, v0r[j].y, vacc.y);
            vacc.z = fmaf(ps, v0r[j].z, vacc.z);
            vacc.w = fmaf(ps, v0r[j].w, vacc.w);
        }
        if (hasb1) {
#pragma unroll
            for (int j = 0; j < 16; ++j) {
                const int s = sg + 4 * j;
                const float ps = __shfl(p1, s, 64);
                float4 v4 = *(const float4*)&Vb1[s * HD + d4 * 4];
                vacc.x = fmaf(ps, v4.x, vacc.x);
                vacc.y = fmaf(ps, v4.y, vacc.y);
                vacc.z = fmaf(ps, v4.z, vacc.z);
                vacc.w = fmaf(ps, v4.w, vacc.w);
            }
        }
    }

    // reduce vacc over the 4 slot subgroups
#pragma unroll
    for (int o = 16; o <= 32; o <<= 1) {
        vacc.x += __shfl_xor(vacc.x, o, 64);
        vacc.y += __shfl_xor(vacc.y, o, 64);
        vacc.z += __shfl_xor(vacc.z, o, 64);
        vacc.w += __shfl_xor(vacc.w, o, 64);
    }
    if (sg == 0) *(float4*)&o_lds[wv][d4 * 4] = vacc;
    if (lane == 0) { ml_lds[wv][0] = m; ml_lds[wv][1] = lsum; }
    __syncthreads();

    if (wv == 0) {
        const float qk = wave_sum64(qd * knd);   // new-token score (finite)
        float Mf = qk;
#pragma unroll
        for (int w = 0; w < 4; ++w) Mf = fmaxf(Mf, ml_lds[w][0]);
        float osum = 0.0f, Ls = 0.0f;
#pragma unroll
        for (int w = 0; w < 4; ++w) {
            const float f = __expf(ml_lds[w][0] - Mf);   // 0 for empty waves
            osum = fmaf(o_lds[w][lane], f, osum);
            Ls   = fmaf(ml_lds[w][1], f, Ls);
        }
        const float pn = __expf(qk - Mf);
        osum = fmaf(pn, vnd, osum);
        Ls += pn;
        obuf[(size_t)b * E + h * HD + lane] = osum / Ls;
    }
}

extern "C" void kernel_launch(void* const* d_in, const int* in_sizes, int n_in,
                              void* d_out, int out_size, void* d_ws, size_t ws_size,
                              hipStream_t stream) {
    const float* hidden = (const float*)d_in[0];
    const float* kcache = (const float*)d_in[1];
    const float* vcache = (const float*)d_in[2];
    const float* wq = (const float*)d_in[3];
    const float* bq = (const float*)d_in[4];
    const float* wk = (const float*)d_in[5];
    const float* bk = (const float*)d_in[6];
    const float* wvp = (const float*)d_in[7];
    const float* bv = (const float*)d_in[8];
    const float* wo = (const float*)d_in[9];
    const float* bo = (const float*)d_in[10];
    const int* cpos = (const int*)d_in[11];
    const int* btab = (const int*)d_in[12];
    float* out = (float*)d_out;

    // ws footprint: 64*3840 + 64*1280 floats = 1.31 MB (proven safe)
    float* ws = (float*)d_ws;
    float* qkv = ws;                  // 64 x 3840 (q|k|v, bias+scale applied)
    float* ob  = ws + 64 * 3 * E;     // 64 x 1280

    // fused QKV projection: 240 blocks of 64x16
    mfma_gemm<3 * E, true><<<(3 * E) / 16, 256, 0, stream>>>(
        hidden, wq, wk, wvp, bq, bk, bv, qkv);
    // attention: one block per (b,h)
    attn_kernel<<<NBATCH * NHEAD, 256, 0, stream>>>(qkv, kcache, vcache, cpos, btab, ob);
    // output projection: 80 blocks of 64x16, bias fused, direct to d_out
    mfma_gemm<E, false><<<E / 16, 256, 0, stream>>>(
        ob, wo, wo, wo, bo, bo, bo, out);
}